// Round 1
// baseline (26212.860 us; speedup 1.0000x reference)
//
#include <hip/hip_runtime.h>
#include <hip/hip_bf16.h>
#include <cstdint>

#define BB 128
#define LL 256
#define VV 50000
#define DD 300
#define HH 512
#define TOUT 511   // 256+128+...+1

constexpr int MT = 64;   // rows per block
constexpr int NT = 64;   // h-cols per block (x5 gate strips = 320 gate cols)
constexpr int KT = 16;   // K chunk

__device__ __forceinline__ float sigf(float x){ return 1.0f/(1.0f+__expf(-x)); }
__device__ __forceinline__ float tanh_fast(float x){ return 1.0f - 2.0f/(__expf(2.0f*x)+1.0f); }

// ---------------- Level 0: h,c = cell(emb[tok] @ Wx + b, zeros) ----------------
__global__ __launch_bounds__(256) void lvl0(const int* __restrict__ tok,
    const float* __restrict__ emb, const float* __restrict__ Wx,
    const float* __restrict__ bias, float* out, float* __restrict__ cbuf)
{
  __shared__ float At[MT][KT+1];
  __shared__ float Wt[KT][5*NT];
  __shared__ int toks[MT];
  const int tid = threadIdx.x;
  const int r0 = blockIdx.x * MT;
  const int n0 = blockIdx.y * NT;
  const int ty = tid >> 4, tx = tid & 15;
  if (tid < MT) toks[tid] = tok[r0 + tid];

  float acc[5][4][4];
  #pragma unroll
  for (int g=0; g<5; g++)
    #pragma unroll
    for (int r=0;r<4;r++)
      #pragma unroll
      for (int c=0;c<4;c++) acc[g][r][c]=0.f;

  __syncthreads();
  for (int k0 = 0; k0 < DD; k0 += KT) {
    // stage A (gathered embedding rows), [row][k] layout, coalesced 64B/row-chunk
    #pragma unroll
    for (int i=0;i<4;i++){
      int idx = tid + i*256;
      int rr = idx >> 4, kk = idx & 15;
      int k = k0 + kk;
      At[rr][kk] = (k < DD) ? emb[(size_t)toks[rr]*DD + k] : 0.f;
    }
    // stage Wx: 5 gate strips of 64 cols
    #pragma unroll
    for (int i=0;i<20;i++){
      int idx = tid + i*256;
      int kk = idx / 320, c = idx - kk*320;
      int k = k0 + kk;
      int g = c >> 6, j = c & 63;
      Wt[kk][c] = (k < DD) ? Wx[(size_t)k*2560 + g*HH + n0 + j] : 0.f;
    }
    __syncthreads();
    #pragma unroll
    for (int kk=0; kk<KT; kk++){
      float a[4];
      #pragma unroll
      for (int r=0;r<4;r++) a[r] = At[ty*4+r][kk];
      #pragma unroll
      for (int g=0;g<5;g++){
        const float4 w = *reinterpret_cast<const float4*>(&Wt[kk][g*64 + tx*4]);
        #pragma unroll
        for (int r=0;r<4;r++){
          acc[g][r][0] += a[r]*w.x; acc[g][r][1] += a[r]*w.y;
          acc[g][r][2] += a[r]*w.z; acc[g][r][3] += a[r]*w.w;
        }
      }
    }
    __syncthreads();
  }
  // epilogue: gates -> c,h (hl=hr=cl=cr=0)
  float bi[5][4];
  #pragma unroll
  for (int g=0;g<5;g++){
    const float4 b4 = *reinterpret_cast<const float4*>(&bias[g*HH + n0 + tx*4]);
    bi[g][0]=b4.x; bi[g][1]=b4.y; bi[g][2]=b4.z; bi[g][3]=b4.w;
  }
  #pragma unroll
  for (int r=0;r<4;r++){
    int row = r0 + ty*4 + r;
    int b = row >> 8, t = row & 255;
    float hv[4], cv[4];
    #pragma unroll
    for (int c=0;c<4;c++){
      float gi = acc[0][r][c]+bi[0][c];
      float go = acc[3][r][c]+bi[3][c];
      float gu = acc[4][r][c]+bi[4][c];
      float cc = sigf(gi)*tanh_fast(gu);
      cv[c]=cc; hv[c]=sigf(go)*tanh_fast(cc);
    }
    *reinterpret_cast<float4*>(&out[((size_t)b*TOUT + t)*HH + n0 + tx*4])
        = make_float4(hv[0],hv[1],hv[2],hv[3]);
    *reinterpret_cast<float4*>(&cbuf[(size_t)row*HH + n0 + tx*4])
        = make_float4(cv[0],cv[1],cv[2],cv[3]);
  }
}

// ---------------- Levels 1..8: h,c = cell(hl@Ul + hr@Ur + b, cl, cr) ----------------
__global__ __launch_bounds__(256) void lvlk(const float* out_ro,
    const float* __restrict__ cprev, const float* __restrict__ Ul,
    const float* __restrict__ Ur, const float* __restrict__ bias,
    float* out, float* __restrict__ cnext,
    int Lk, int sp, int sc)
{
  __shared__ float Al[MT][KT+1];
  __shared__ float Ar[MT][KT+1];
  __shared__ float Wl[KT][5*NT];
  __shared__ float Wr[KT][5*NT];
  __shared__ size_t hbase[MT];
  __shared__ size_t cbase[MT];
  const int tid = threadIdx.x;
  const int r0 = blockIdx.x * MT;
  const int n0 = blockIdx.y * NT;
  const int ty = tid >> 4, tx = tid & 15;
  if (tid < MT){
    int row = r0 + tid;
    int b = row / Lk, t = row - b*Lk;
    hbase[tid] = ((size_t)b*TOUT + sp + 2*t)*HH;
    cbase[tid] = ((size_t)b*(2*Lk) + 2*t)*HH;
  }
  float acc[5][4][4];
  #pragma unroll
  for (int g=0; g<5; g++)
    #pragma unroll
    for (int r=0;r<4;r++)
      #pragma unroll
      for (int c=0;c<4;c++) acc[g][r][c]=0.f;

  __syncthreads();
  for (int k0 = 0; k0 < HH; k0 += KT) {
    #pragma unroll
    for (int i=0;i<4;i++){
      int idx = tid + i*256;
      int rr = idx >> 4, kk = idx & 15;
      Al[rr][kk] = out_ro[hbase[rr] + k0 + kk];
      Ar[rr][kk] = out_ro[hbase[rr] + HH + k0 + kk];
    }
    #pragma unroll
    for (int i=0;i<20;i++){
      int idx = tid + i*256;
      int kk = idx / 320, c = idx - kk*320;
      int g = c >> 6, j = c & 63;
      size_t wi = (size_t)(k0+kk)*2560 + g*HH + n0 + j;
      Wl[kk][c] = Ul[wi];
      Wr[kk][c] = Ur[wi];
    }
    __syncthreads();
    #pragma unroll
    for (int kk=0; kk<KT; kk++){
      float al[4], ar[4];
      #pragma unroll
      for (int r=0;r<4;r++){ al[r] = Al[ty*4+r][kk]; ar[r] = Ar[ty*4+r][kk]; }
      #pragma unroll
      for (int g=0;g<5;g++){
        const float4 wl4 = *reinterpret_cast<const float4*>(&Wl[kk][g*64 + tx*4]);
        const float4 wr4 = *reinterpret_cast<const float4*>(&Wr[kk][g*64 + tx*4]);
        #pragma unroll
        for (int r=0;r<4;r++){
          acc[g][r][0] += al[r]*wl4.x + ar[r]*wr4.x;
          acc[g][r][1] += al[r]*wl4.y + ar[r]*wr4.y;
          acc[g][r][2] += al[r]*wl4.z + ar[r]*wr4.z;
          acc[g][r][3] += al[r]*wl4.w + ar[r]*wr4.w;
        }
      }
    }
    __syncthreads();
  }
  float bi[5][4];
  #pragma unroll
  for (int g=0;g<5;g++){
    const float4 b4 = *reinterpret_cast<const float4*>(&bias[g*HH + n0 + tx*4]);
    bi[g][0]=b4.x; bi[g][1]=b4.y; bi[g][2]=b4.z; bi[g][3]=b4.w;
  }
  #pragma unroll
  for (int r=0;r<4;r++){
    int rr = ty*4 + r;
    int row = r0 + rr;
    int b = row / Lk, t = row - b*Lk;
    const float4 cl4 = *reinterpret_cast<const float4*>(&cprev[cbase[rr] + n0 + tx*4]);
    const float4 cr4 = *reinterpret_cast<const float4*>(&cprev[cbase[rr] + HH + n0 + tx*4]);
    float cl[4] = {cl4.x, cl4.y, cl4.z, cl4.w};
    float cr[4] = {cr4.x, cr4.y, cr4.z, cr4.w};
    float hv[4], cv[4];
    #pragma unroll
    for (int c=0;c<4;c++){
      float gi = acc[0][r][c]+bi[0][c];
      float gfl= acc[1][r][c]+bi[1][c];
      float gfr= acc[2][r][c]+bi[2][c];
      float go = acc[3][r][c]+bi[3][c];
      float gu = acc[4][r][c]+bi[4][c];
      float cc = sigf(gi)*tanh_fast(gu) + sigf(gfl)*cl[c] + sigf(gfr)*cr[c];
      cv[c]=cc; hv[c]=sigf(go)*tanh_fast(cc);
    }
    *reinterpret_cast<float4*>(&out[((size_t)b*TOUT + sc + t)*HH + n0 + tx*4])
        = make_float4(hv[0],hv[1],hv[2],hv[3]);
    *reinterpret_cast<float4*>(&cnext[((size_t)b*Lk + t)*HH + n0 + tx*4])
        = make_float4(cv[0],cv[1],cv[2],cv[3]);
  }
}

extern "C" void kernel_launch(void* const* d_in, const int* in_sizes, int n_in,
                              void* d_out, int out_size, void* d_ws, size_t ws_size,
                              hipStream_t stream) {
  (void)in_sizes; (void)n_in; (void)out_size; (void)ws_size;
  const int*   tok  = (const int*)d_in[0];
  const float* emb  = (const float*)d_in[1];
  const float* Wx   = (const float*)d_in[2];
  const float* Ul   = (const float*)d_in[3];
  const float* Ur   = (const float*)d_in[4];
  const float* bias = (const float*)d_in[5];
  float* out = (float*)d_out;
  float* cA = (float*)d_ws;                       // level-0 c: 128*256*512 f32 = 64 MiB
  float* cB = cA + (size_t)BB*LL*HH;              // odd-level c: <= 32 MiB

  lvl0<<<dim3((BB*LL)/MT, HH/NT), 256, 0, stream>>>(tok, emb, Wx, bias, out, cA);
  for (int k=1; k<=8; k++){
    int Lk = LL >> k;
    int sp = 512 - (512 >> (k-1));   // start offset of level k-1 h in out
    int sc = 512 - (512 >> k);       // start offset of level k h in out
    const float* cin = (k & 1) ? cA : cB;
    float*       co  = (k & 1) ? cB : cA;
    lvlk<<<dim3((BB*Lk)/MT, HH/NT), 256, 0, stream>>>(out, cin, Ul, Ur, bias, out, co, Lk, sp, sc);
  }
}

// Round 2
// 593.051 us; speedup vs baseline: 44.2000x; 44.2000x over previous
//
#include <hip/hip_runtime.h>
#include <hip/hip_bf16.h>
#include <cstdint>

#define BB 128
#define LL 256
#define DD 300
#define HH 512
#define TOUT 511
#define NGATE 2560   // 5*H

typedef __attribute__((ext_vector_type(8))) short bf16x8;
typedef __attribute__((ext_vector_type(4))) float f32x4;

__device__ __forceinline__ float sigf(float x){ return 1.0f/(1.0f+__expf(-x)); }
__device__ __forceinline__ float tanh_fast(float x){ return 1.0f - 2.0f/(__expf(2.0f*x)+1.0f); }

__device__ __forceinline__ void load_lds16(const void* g, void* l) {
  __builtin_amdgcn_global_load_lds(
      (const __attribute__((address_space(1))) unsigned int*)g,
      (__attribute__((address_space(3))) unsigned int*)l, 16, 0, 0);
}

// ---- transpose+convert: src f32 [Ksrc][2560] -> dst bf16 [2560][Kdst], dst[n][koff+k]=src[k][n]
__global__ __launch_bounds__(256) void transpose_cvt(const float* __restrict__ src,
    __hip_bfloat16* __restrict__ dst, int Ksrc, int Kdst, int koff)
{
  __shared__ float t[64][65];
  const int tid = threadIdx.x;
  const int k0 = blockIdx.x * 64;
  const int n0 = blockIdx.y * 64;
  #pragma unroll
  for (int p = 0; p < 16; ++p) {
    int lin = p*256 + tid;
    int ki = lin >> 6, nj = lin & 63;
    t[ki][nj] = (k0 + ki < Ksrc) ? src[(size_t)(k0+ki)*NGATE + n0 + nj] : 0.f;
  }
  __syncthreads();
  #pragma unroll
  for (int p = 0; p < 16; ++p) {
    int lin = p*256 + tid;
    int ni = lin >> 6, kj = lin & 63;
    dst[(size_t)(n0+ni)*Kdst + koff + k0 + kj] = __float2bfloat16(t[kj][ni]);
  }
}

// ---- embedding gather + cvt: A0 bf16 [32768][320]
__global__ void embed_cvt(const int* __restrict__ tok, const float* __restrict__ emb,
                          __hip_bfloat16* __restrict__ A0)
{
  int k = blockIdx.x * 64 + threadIdx.x;
  int r = blockIdx.y * 4 + threadIdx.y;
  int tk = tok[r];
  float v = (k < DD) ? emb[(size_t)tk*DD + k] : 0.f;
  A0[(size_t)r*320 + k] = __float2bfloat16(v);
}

// ---- fused GEMM + tree-LSTM cell
// A bf16 [M][K], Wt bf16 [2560][K] (transposed weights), K in {320,1024}
// block: 64 rows x 64 h-cols (320 gate cols). 4 waves 2x2 (wm in rows, wn gate-aligned in h-cols)
__global__ __launch_bounds__(256) void gemm_cell(
    const __hip_bfloat16* __restrict__ A, const __hip_bfloat16* __restrict__ Wt,
    int K, const float* __restrict__ bias, const float* __restrict__ cprev,
    float* __restrict__ out, __hip_bfloat16* __restrict__ hout, float* __restrict__ cout,
    int lkshift, int sc)
{
  __shared__ __align__(16) char lds[49152];   // At 64x64 bf16 (8KB) + Bt 320x64 bf16 (40KB)
  char* AtB = lds;
  char* BtB = lds + 8192;

  const int tid  = threadIdx.x;
  const int lane = tid & 63;
  const int wid  = tid >> 6;
  const int wm   = wid >> 1;
  const int wn   = wid & 1;
  const int r0   = blockIdx.x * 64;
  const int n0   = blockIdx.y * 64;

  f32x4 acc[2][5][2];
  #pragma unroll
  for (int mf = 0; mf < 2; ++mf)
    #pragma unroll
    for (int g5 = 0; g5 < 5; ++g5)
      #pragma unroll
      for (int f = 0; f < 2; ++f)
        acc[mf][g5][f] = (f32x4){0.f,0.f,0.f,0.f};

  // per-lane staging geometry (T2 swizzle via pre-swizzled global source, rule 21)
  const int srow = lane >> 3;                    // 0..7 row within issue
  const int gq   = (lane & 7) ^ (srow & 7);      // swizzled 16B chunk in the 128B row
  const int nk = K >> 6;

  for (int kt = 0; kt < nk; ++kt) {
    const int k0 = kt << 6;
    // stage A: 8 issues of 1KB (issue i -> tile rows 8i..8i+7); wave wid does 2
    #pragma unroll
    for (int ii = 0; ii < 2; ++ii) {
      int issue = wid*2 + ii;
      int r = issue*8 + srow;
      const char* g = (const char*)A + ((size_t)(r0 + r)*K + k0)*2 + (size_t)gq*16;
      load_lds16(g, AtB + issue*1024);
    }
    // stage B: 40 issues; wave wid does 10. tile row c -> global gate col g*512+n0+(c&63)
    #pragma unroll
    for (int ii = 0; ii < 10; ++ii) {
      int issue = wid*10 + ii;
      int c = issue*8 + srow;
      int gg = c >> 6, j = c & 63;
      const char* g = (const char*)Wt + ((size_t)(gg*512 + n0 + j)*K + k0)*2 + (size_t)gq*16;
      load_lds16(g, BtB + issue*1024);
    }
    __syncthreads();

    #pragma unroll
    for (int s = 0; s < 2; ++s) {
      const int qbase = s*4 + (lane >> 4);       // global 16B chunk index (k = chunk*8..+8)
      bf16x8 a[2], b[5][2];
      #pragma unroll
      for (int mf = 0; mf < 2; ++mf) {
        int r = wm*32 + mf*16 + (lane & 15);
        int q = qbase ^ (r & 7);
        a[mf] = *(const bf16x8*)(AtB + r*128 + q*16);
      }
      #pragma unroll
      for (int g5 = 0; g5 < 5; ++g5)
        #pragma unroll
        for (int f = 0; f < 2; ++f) {
          int c = g5*64 + wn*32 + f*16 + (lane & 15);
          int q = qbase ^ (c & 7);
          b[g5][f] = *(const bf16x8*)(BtB + c*128 + q*16);
        }
      #pragma unroll
      for (int mf = 0; mf < 2; ++mf)
        #pragma unroll
        for (int g5 = 0; g5 < 5; ++g5)
          #pragma unroll
          for (int f = 0; f < 2; ++f)
            acc[mf][g5][f] = __builtin_amdgcn_mfma_f32_16x16x32_bf16(
                a[mf], b[g5][f], acc[mf][g5][f], 0, 0, 0);
    }
    __syncthreads();
  }

  // epilogue: fused LSTM cell
  const int Lmask = (1 << lkshift) - 1;
  #pragma unroll
  for (int f = 0; f < 2; ++f) {
    const int jg = n0 + wn*32 + f*16 + (lane & 15);
    float bia[5];
    #pragma unroll
    for (int g5 = 0; g5 < 5; ++g5) bia[g5] = bias[g5*HH + jg];
    #pragma unroll
    for (int mf = 0; mf < 2; ++mf) {
      #pragma unroll
      for (int v = 0; v < 4; ++v) {
        int r = r0 + wm*32 + mf*16 + (lane >> 4)*4 + v;
        float gi  = acc[mf][0][f][v] + bia[0];
        float gfl = acc[mf][1][f][v] + bia[1];
        float gfr = acc[mf][2][f][v] + bia[2];
        float go  = acc[mf][3][f][v] + bia[3];
        float gu  = acc[mf][4][f][v] + bia[4];
        float cl = 0.f, cr = 0.f;
        if (cprev) {
          cl = cprev[(size_t)(2*r)*HH + jg];
          cr = cprev[(size_t)(2*r)*HH + HH + jg];
        }
        float cc = sigf(gi)*tanh_fast(gu) + sigf(gfl)*cl + sigf(gfr)*cr;
        float hh = sigf(go)*tanh_fast(cc);
        int b = r >> lkshift;
        int t = r & Lmask;
        out[((size_t)b*TOUT + sc + t)*HH + jg] = hh;
        hout[(size_t)r*HH + jg] = __float2bfloat16(hh);
        cout[(size_t)r*HH + jg] = cc;
      }
    }
  }
}

extern "C" void kernel_launch(void* const* d_in, const int* in_sizes, int n_in,
                              void* d_out, int out_size, void* d_ws, size_t ws_size,
                              hipStream_t stream) {
  (void)in_sizes; (void)n_in; (void)out_size; (void)ws_size;
  const int*   tok  = (const int*)d_in[0];
  const float* emb  = (const float*)d_in[1];
  const float* Wx   = (const float*)d_in[2];
  const float* Ul   = (const float*)d_in[3];
  const float* Ur   = (const float*)d_in[4];
  const float* bias = (const float*)d_in[5];
  float* out = (float*)d_out;

  char* ws = (char*)d_ws;
  size_t off = 0;
  __hip_bfloat16* Wb0t = (__hip_bfloat16*)(ws + off); off += (size_t)NGATE*320*2;   // 1.6 MB
  __hip_bfloat16* Wb1t = (__hip_bfloat16*)(ws + off); off += (size_t)NGATE*1024*2;  // 5.2 MB
  __hip_bfloat16* hA   = (__hip_bfloat16*)(ws + off); off += (size_t)32768*HH*2;    // 32 MB (even levels)
  __hip_bfloat16* hB   = (__hip_bfloat16*)(ws + off); off += (size_t)16384*HH*2;    // 16 MB (odd levels)
  float*          cA   = (float*)(ws + off);          off += (size_t)32768*HH*4;    // 64 MB (even levels)
  float*          cB   = (float*)(ws + off);          off += (size_t)16384*HH*4;    // 32 MB (odd levels)
  __hip_bfloat16* A0   = (__hip_bfloat16*)cB;   // alias: A0 dead before cB first written (level 1)

  // weight prep (bf16, transposed [N][K])
  transpose_cvt<<<dim3(5, 40), 256, 0, stream>>>(Wx, Wb0t, DD, 320, 0);
  transpose_cvt<<<dim3(8, 40), 256, 0, stream>>>(Ul, Wb1t, HH, 1024, 0);
  transpose_cvt<<<dim3(8, 40), 256, 0, stream>>>(Ur, Wb1t, HH, 1024, 512);
  // embedding gather -> bf16 A0 [32768][320]
  embed_cvt<<<dim3(5, 8192), dim3(64,4), 0, stream>>>(tok, emb, A0);

  // level 0: M=32768, K=320
  gemm_cell<<<dim3(512, 8), 256, 0, stream>>>(A0, Wb0t, 320, bias, nullptr,
                                              out, hA, cA, 8, 0);
  // levels 1..8: M = 32768>>k, K=1024
  for (int k = 1; k <= 8; ++k) {
    int M = 32768 >> k;
    int sc = HH - (HH >> k);
    const __hip_bfloat16* Ain = (k & 1) ? hA : hB;
    __hip_bfloat16*       hO  = (k & 1) ? hB : hA;
    const float*          cI  = (k & 1) ? cA : cB;
    float*                cO  = (k & 1) ? cB : cA;
    gemm_cell<<<dim3(M/64, 8), 256, 0, stream>>>(Ain, Wb1t, 1024, bias, cI,
                                                 out, hO, cO, 8 - k, sc);
  }
}

// Round 3
// 543.239 us; speedup vs baseline: 48.2529x; 1.0917x over previous
//
#include <hip/hip_runtime.h>
#include <hip/hip_bf16.h>
#include <cstdint>

#define BB 128
#define LL 256
#define DD 300
#define HH 512
#define TOUT 511
#define NGATE 2560   // 5*H

typedef __attribute__((ext_vector_type(8))) short bf16x8;
typedef __attribute__((ext_vector_type(4))) float f32x4;

__device__ __forceinline__ float sigf(float x){ return 1.0f/(1.0f+__expf(-x)); }
__device__ __forceinline__ float tanh_fast(float x){ return 1.0f - 2.0f/(__expf(2.0f*x)+1.0f); }

__device__ __forceinline__ void load_lds16(const void* g, void* l) {
  __builtin_amdgcn_global_load_lds(
      (const __attribute__((address_space(1))) unsigned int*)g,
      (__attribute__((address_space(3))) unsigned int*)l, 16, 0, 0);
}

// ---- transpose+convert: src f32 [Ksrc][2560] -> dst bf16 [2560][Kdst], dst[n][koff+k]=src[k][n]
__global__ __launch_bounds__(256) void transpose_cvt(const float* __restrict__ src,
    __hip_bfloat16* __restrict__ dst, int Ksrc, int Kdst, int koff)
{
  __shared__ float t[64][65];
  const int tid = threadIdx.x;
  const int k0 = blockIdx.x * 64;
  const int n0 = blockIdx.y * 64;
  #pragma unroll
  for (int p = 0; p < 16; ++p) {
    int lin = p*256 + tid;
    int ki = lin >> 6, nj = lin & 63;
    t[ki][nj] = (k0 + ki < Ksrc) ? src[(size_t)(k0+ki)*NGATE + n0 + nj] : 0.f;
  }
  __syncthreads();
  #pragma unroll
  for (int p = 0; p < 16; ++p) {
    int lin = p*256 + tid;
    int ni = lin >> 6, kj = lin & 63;
    dst[(size_t)(n0+ni)*Kdst + koff + k0 + kj] = __float2bfloat16(t[kj][ni]);
  }
}

// ---- embedding gather + cvt: A0 bf16 [32768][320]
__global__ void embed_cvt(const int* __restrict__ tok, const float* __restrict__ emb,
                          __hip_bfloat16* __restrict__ A0)
{
  int k = blockIdx.x * 64 + threadIdx.x;
  int r = blockIdx.y * 4 + threadIdx.y;
  int tk = tok[r];
  float v = (k < DD) ? emb[(size_t)tk*DD + k] : 0.f;
  A0[(size_t)r*320 + k] = __float2bfloat16(v);
}

// ---- fused GEMM + tree-LSTM cell, 2-phase pipelined (T3 minimum recipe)
// A bf16 [M][K], Wt bf16 [2560][K] (transposed weights), K in {320,1024}
// block: 128 rows x 64 h-cols (320 gate cols). 8 waves: 2(m) x 4(n, gate-aligned)
// per wave: 64 rows x (16 h-cols x 5 gates) -> acc[4][5] f32x4
__global__ __launch_bounds__(512) void gemm_cell(
    const __hip_bfloat16* __restrict__ A, const __hip_bfloat16* __restrict__ Wt,
    int K, const float* __restrict__ bias, const float* __restrict__ cprev,
    float* __restrict__ out, __hip_bfloat16* __restrict__ hout, float* __restrict__ cout,
    int lkshift, int sc)
{
  // per buffer: A-tile 128x64 bf16 = 16KB, B-tile 320x64 bf16 = 40KB -> 56KB; x2 dbuf = 112KB
  __shared__ __align__(16) char lds[114688];
  constexpr int BUFS = 57344;

  const int tid  = threadIdx.x;
  const int lane = tid & 63;
  const int wid  = tid >> 6;     // 0..7
  const int wm   = wid >> 2;     // 0..1  (64-row half)
  const int wn   = wid & 3;      // 0..3  (16 h-col strip, gate-aligned)
  const int r0   = blockIdx.x * 128;
  const int n0   = blockIdx.y * 64;

  f32x4 acc[4][5];
  #pragma unroll
  for (int mf = 0; mf < 4; ++mf)
    #pragma unroll
    for (int g5 = 0; g5 < 5; ++g5)
      acc[mf][g5] = (f32x4){0.f,0.f,0.f,0.f};

  // staging geometry (pre-swizzled global source, linear LDS dest — rule 21)
  const int srow = lane >> 3;              // 0..7 row within 1KB issue
  const int gq   = (lane & 7) ^ srow;      // swizzled 16B chunk within 128B row
  const int nk = K >> 6;

  // 56 issues of 1KB per K-tile: A = 0..15 (8 rows each), B = 16..55. 7 per wave.
  auto stage = [&](int buf, int kt){
    const int k0 = kt << 6;
    char* base = lds + buf*BUFS;
    #pragma unroll
    for (int ii = 0; ii < 7; ++ii) {
      int issue = wid*7 + ii;
      if (issue < 16) {
        int r = issue*8 + srow;
        const char* g = (const char*)A + ((size_t)(r0 + r)*K + k0)*2 + (size_t)gq*16;
        load_lds16(g, base + issue*1024);
      } else {
        int c = (issue-16)*8 + srow;               // B-tile row 0..319
        int gg = c >> 6, j = c & 63;
        const char* g = (const char*)Wt + ((size_t)(gg*512 + n0 + j)*K + k0)*2 + (size_t)gq*16;
        load_lds16(g, base + 16384 + (issue-16)*1024);
      }
    }
  };

  stage(0, 0);
  __syncthreads();
  int cur = 0;
  for (int kt = 0; kt < nk; ++kt) {
    if (kt + 1 < nk) stage(cur ^ 1, kt + 1);   // issue next-tile loads FIRST (overlap MFMA)
    const char* Ab = lds + cur*BUFS;
    const char* Bb = Ab + 16384;
    #pragma unroll
    for (int s = 0; s < 2; ++s) {
      const int qbase = s*4 + (lane >> 4);
      bf16x8 a[4], b[5];
      #pragma unroll
      for (int mf = 0; mf < 4; ++mf) {
        int r = wm*64 + mf*16 + (lane & 15);
        int q = qbase ^ (r & 7);
        a[mf] = *(const bf16x8*)(Ab + r*128 + q*16);
      }
      #pragma unroll
      for (int g5 = 0; g5 < 5; ++g5) {
        int c = g5*64 + wn*16 + (lane & 15);
        int q = qbase ^ (c & 7);
        b[g5] = *(const bf16x8*)(Bb + c*128 + q*16);
      }
      #pragma unroll
      for (int mf = 0; mf < 4; ++mf)
        #pragma unroll
        for (int g5 = 0; g5 < 5; ++g5)
          acc[mf][g5] = __builtin_amdgcn_mfma_f32_16x16x32_bf16(a[mf], b[g5], acc[mf][g5], 0, 0, 0);
    }
    __syncthreads();   // single drain per K-tile: vmcnt(0) covers next-tile staging
    cur ^= 1;
  }

  // epilogue: fused LSTM cell
  const int Lmask = (1 << lkshift) - 1;
  const int jg = n0 + wn*16 + (lane & 15);
  float bia[5];
  #pragma unroll
  for (int g5 = 0; g5 < 5; ++g5) bia[g5] = bias[g5*HH + jg];
  #pragma unroll
  for (int mf = 0; mf < 4; ++mf) {
    #pragma unroll
    for (int v = 0; v < 4; ++v) {
      int r = r0 + wm*64 + mf*16 + (lane >> 4)*4 + v;
      float gi  = acc[mf][0][v] + bia[0];
      float gfl = acc[mf][1][v] + bia[1];
      float gfr = acc[mf][2][v] + bia[2];
      float go  = acc[mf][3][v] + bia[3];
      float gu  = acc[mf][4][v] + bia[4];
      float cl = 0.f, cr = 0.f;
      if (cprev) {
        cl = cprev[(size_t)(2*r)*HH + jg];
        cr = cprev[(size_t)(2*r)*HH + HH + jg];
      }
      float cc = sigf(gi)*tanh_fast(gu) + sigf(gfl)*cl + sigf(gfr)*cr;
      float hh = sigf(go)*tanh_fast(cc);
      int b = r >> lkshift;
      int t = r & Lmask;
      out[((size_t)b*TOUT + sc + t)*HH + jg] = hh;
      hout[(size_t)r*HH + jg] = __float2bfloat16(hh);
      cout[(size_t)r*HH + jg] = cc;
    }
  }
}

extern "C" void kernel_launch(void* const* d_in, const int* in_sizes, int n_in,
                              void* d_out, int out_size, void* d_ws, size_t ws_size,
                              hipStream_t stream) {
  (void)in_sizes; (void)n_in; (void)out_size; (void)ws_size;
  const int*   tok  = (const int*)d_in[0];
  const float* emb  = (const float*)d_in[1];
  const float* Wx   = (const float*)d_in[2];
  const float* Ul   = (const float*)d_in[3];
  const float* Ur   = (const float*)d_in[4];
  const float* bias = (const float*)d_in[5];
  float* out = (float*)d_out;

  char* ws = (char*)d_ws;
  size_t off = 0;
  __hip_bfloat16* Wb0t = (__hip_bfloat16*)(ws + off); off += (size_t)NGATE*320*2;   // 1.6 MB
  __hip_bfloat16* Wb1t = (__hip_bfloat16*)(ws + off); off += (size_t)NGATE*1024*2;  // 5.2 MB
  __hip_bfloat16* hA   = (__hip_bfloat16*)(ws + off); off += (size_t)32768*HH*2;    // 32 MB (even levels)
  __hip_bfloat16* hB   = (__hip_bfloat16*)(ws + off); off += (size_t)16384*HH*2;    // 16 MB (odd levels)
  float*          cA   = (float*)(ws + off);          off += (size_t)32768*HH*4;    // 64 MB (even levels)
  float*          cB   = (float*)(ws + off);          off += (size_t)16384*HH*4;    // 32 MB (odd levels)
  __hip_bfloat16* A0   = (__hip_bfloat16*)cB;   // alias: A0 dead before cB first written (level 1)

  // weight prep (bf16, transposed [N][K])
  transpose_cvt<<<dim3(5, 40), 256, 0, stream>>>(Wx, Wb0t, DD, 320, 0);
  transpose_cvt<<<dim3(8, 40), 256, 0, stream>>>(Ul, Wb1t, HH, 1024, 0);
  transpose_cvt<<<dim3(8, 40), 256, 0, stream>>>(Ur, Wb1t, HH, 1024, 512);
  // embedding gather -> bf16 A0 [32768][320]
  embed_cvt<<<dim3(5, 8192), dim3(64,4), 0, stream>>>(tok, emb, A0);

  // level 0: M=32768, K=320
  gemm_cell<<<dim3(256, 8), 512, 0, stream>>>(A0, Wb0t, 320, bias, nullptr,
                                              out, hA, cA, 8, 0);
  // levels 1..8: M = 32768>>k, K=1024
  for (int k = 1; k <= 8; ++k) {
    int M = 32768 >> k;
    int sc = HH - (HH >> k);
    const __hip_bfloat16* Ain = (k & 1) ? hA : hB;
    __hip_bfloat16*       hO  = (k & 1) ? hB : hA;
    const float*          cI  = (k & 1) ? cA : cB;
    float*                cO  = (k & 1) ? cB : cA;
    int mblk = (M + 127) / 128;
    gemm_cell<<<dim3(mblk, 8), 512, 0, stream>>>(Ain, Wb1t, 1024, bias, cI,
                                                 out, hO, cO, 8 - k, sc);
  }
}

// Round 4
// 535.987 us; speedup vs baseline: 48.9058x; 1.0135x over previous
//
#include <hip/hip_runtime.h>
#include <hip/hip_bf16.h>
#include <cstdint>

#define BB 128
#define LL 256
#define DD 300
#define HH 512
#define TOUT 511
#define NGATE 2560   // 5*H

typedef __attribute__((ext_vector_type(8))) short bf16x8;
typedef __attribute__((ext_vector_type(4))) float f32x4;

__device__ __forceinline__ float sigf(float x){ return 1.0f/(1.0f+__expf(-x)); }
__device__ __forceinline__ float tanh_fast(float x){ return 1.0f - 2.0f/(__expf(2.0f*x)+1.0f); }

__device__ __forceinline__ void load_lds16(const void* g, void* l) {
  __builtin_amdgcn_global_load_lds(
      (const __attribute__((address_space(1))) unsigned int*)g,
      (__attribute__((address_space(3))) unsigned int*)l, 16, 0, 0);
}

// ---- transpose+convert: src f32 [Ksrc][2560] -> dst bf16 [2560][Kdst], dst[n][koff+k]=src[k][n]
__global__ __launch_bounds__(256) void transpose_cvt(const float* __restrict__ src,
    __hip_bfloat16* __restrict__ dst, int Ksrc, int Kdst, int koff)
{
  __shared__ float t[64][65];
  const int tid = threadIdx.x;
  const int k0 = blockIdx.x * 64;
  const int n0 = blockIdx.y * 64;
  #pragma unroll
  for (int p = 0; p < 16; ++p) {
    int lin = p*256 + tid;
    int ki = lin >> 6, nj = lin & 63;
    t[ki][nj] = (k0 + ki < Ksrc) ? src[(size_t)(k0+ki)*NGATE + n0 + nj] : 0.f;
  }
  __syncthreads();
  #pragma unroll
  for (int p = 0; p < 16; ++p) {
    int lin = p*256 + tid;
    int ni = lin >> 6, kj = lin & 63;
    dst[(size_t)(n0+ni)*Kdst + koff + k0 + kj] = __float2bfloat16(t[kj][ni]);
  }
}

// ---- embedding gather + cvt: A0 bf16 [32768][320]
__global__ void embed_cvt(const int* __restrict__ tok, const float* __restrict__ emb,
                          __hip_bfloat16* __restrict__ A0)
{
  int k = blockIdx.x * 64 + threadIdx.x;
  int r = blockIdx.y * 4 + threadIdx.y;
  int tk = tok[r];
  float v = (k < DD) ? emb[(size_t)tk*DD + k] : 0.f;
  A0[(size_t)r*320 + k] = __float2bfloat16(v);
}

// ---- fused GEMM + tree-LSTM cell, double-buffered with COUNTED vmcnt (T3+T4)
// A bf16 [M][K], Wt bf16 [2560][K]. Block: BM rows x 64 h-cols (320 gate cols).
// 8 waves: 2(m, WM rows each) x 4(n, 16 h-cols gate-aligned).
// Grid 1D = (M/BM)*8; n-strip = bid&7 so each XCD owns one weight strip (T1).
template<int WM>
__global__ __launch_bounds__(512, 2) void gemm_cell(
    const __hip_bfloat16* __restrict__ A, const __hip_bfloat16* __restrict__ Wt,
    int K, const float* __restrict__ bias, const float* __restrict__ cprev,
    float* __restrict__ out, __hip_bfloat16* __restrict__ hout, float* __restrict__ cout,
    int lkshift, int sc)
{
  constexpr int BM     = 2*WM;
  constexpr int ABYTES = BM*128;            // A tile: BM x 64 bf16
  constexpr int BUFS   = ABYTES + 40960;    // + B tile: 320 x 64 bf16
  constexpr int AISS   = BM/8;              // 1KB staging issues for A
  constexpr int NISS   = (AISS + 40)/8;     // issues per wave (9 for WM=128, 7 for WM=64)
  constexpr int MFR    = WM/16;             // m fragments per wave
  __shared__ __align__(16) char lds[2*BUFS];

  const int tid  = threadIdx.x;
  const int lane = tid & 63;
  const int wid  = tid >> 6;     // 0..7
  const int wm   = wid >> 2;     // 0..1
  const int wn   = wid & 3;      // 0..3  (16 h-col strip, gate-aligned)
  const int bid  = blockIdx.x;
  const int r0   = (bid >> 3) * BM;
  const int n0   = (bid & 7) * 64;

  f32x4 acc[MFR][5];
  #pragma unroll
  for (int mf = 0; mf < MFR; ++mf)
    #pragma unroll
    for (int g5 = 0; g5 < 5; ++g5)
      acc[mf][g5] = (f32x4){0.f,0.f,0.f,0.f};

  // staging geometry (pre-swizzled global source, linear LDS dest — rule 21)
  const int srow = lane >> 3;              // 0..7 row within 1KB issue
  const int gq   = (lane & 7) ^ srow;      // swizzled 16B chunk within 128B row
  const int nk   = K >> 6;

  auto stage = [&](int buf, int kt){
    const int k0 = kt << 6;
    char* base = lds + buf*BUFS;
    #pragma unroll
    for (int ii = 0; ii < NISS; ++ii) {
      int issue = wid*NISS + ii;
      if (issue < AISS) {
        int r = issue*8 + srow;
        const char* g = (const char*)A + ((size_t)(r0 + r)*K + k0)*2 + (size_t)gq*16;
        load_lds16(g, base + issue*1024);
      } else {
        int c = (issue-AISS)*8 + srow;               // B-tile row 0..319
        int gg = c >> 6, j = c & 63;
        const char* g = (const char*)Wt + ((size_t)(gg*512 + n0 + j)*K + k0)*2 + (size_t)gq*16;
        load_lds16(g, base + ABYTES + (issue-AISS)*1024);
      }
    }
  };

  stage(0, 0);
  int cur = 0;
  for (int kt = 0; kt < nk; ++kt) {
    if (kt + 1 < nk) {
      stage(cur ^ 1, kt + 1);     // issue next tile: stays IN FLIGHT across barrier+MFMA
      if constexpr (NISS == 9) asm volatile("s_waitcnt vmcnt(9)" ::: "memory");
      else                     asm volatile("s_waitcnt vmcnt(7)" ::: "memory");
    } else {
      asm volatile("s_waitcnt vmcnt(0)" ::: "memory");
    }
    __builtin_amdgcn_s_barrier();   // all waves' cur-tile loads have landed

    const char* Ab = lds + cur*BUFS;
    const char* Bb = Ab + ABYTES;
    __builtin_amdgcn_s_setprio(1);
    #pragma unroll
    for (int s = 0; s < 2; ++s) {
      const int qb = s*4 + (lane >> 4);
      bf16x8 b[5];
      #pragma unroll
      for (int g5 = 0; g5 < 5; ++g5) {
        int c = g5*64 + wn*16 + (lane & 15);
        b[g5] = *(const bf16x8*)(Bb + c*128 + ((qb ^ (c & 7))*16));
      }
      #pragma unroll
      for (int mf = 0; mf < MFR; ++mf) {
        int r = wm*WM + mf*16 + (lane & 15);
        bf16x8 av = *(const bf16x8*)(Ab + r*128 + ((qb ^ (r & 7))*16));
        #pragma unroll
        for (int g5 = 0; g5 < 5; ++g5)
          acc[mf][g5] = __builtin_amdgcn_mfma_f32_16x16x32_bf16(av, b[g5], acc[mf][g5], 0, 0, 0);
      }
    }
    __builtin_amdgcn_s_setprio(0);
    __builtin_amdgcn_s_barrier();   // protect cur buffer before next iteration overwrites
    cur ^= 1;
  }

  // epilogue: fused LSTM cell
  const int Lmask = (1 << lkshift) - 1;
  const int jg = n0 + wn*16 + (lane & 15);
  float bia[5];
  #pragma unroll
  for (int g5 = 0; g5 < 5; ++g5) bia[g5] = bias[g5*HH + jg];
  #pragma unroll
  for (int mf = 0; mf < MFR; ++mf) {
    #pragma unroll
    for (int v = 0; v < 4; ++v) {
      int r = r0 + wm*WM + mf*16 + (lane >> 4)*4 + v;
      float gi  = acc[mf][0][v] + bia[0];
      float gfl = acc[mf][1][v] + bia[1];
      float gfr = acc[mf][2][v] + bia[2];
      float go  = acc[mf][3][v] + bia[3];
      float gu  = acc[mf][4][v] + bia[4];
      float cl = 0.f, cr = 0.f;
      if (cprev) {
        cl = cprev[(size_t)(2*r)*HH + jg];
        cr = cprev[(size_t)(2*r)*HH + HH + jg];
      }
      float cc = sigf(gi)*tanh_fast(gu) + sigf(gfl)*cl + sigf(gfr)*cr;
      float hh = sigf(go)*tanh_fast(cc);
      int b = r >> lkshift;
      int t = r & Lmask;
      out[((size_t)b*TOUT + sc + t)*HH + jg] = hh;
      hout[(size_t)r*HH + jg] = __float2bfloat16(hh);
      cout[(size_t)r*HH + jg] = cc;
    }
  }
}

extern "C" void kernel_launch(void* const* d_in, const int* in_sizes, int n_in,
                              void* d_out, int out_size, void* d_ws, size_t ws_size,
                              hipStream_t stream) {
  (void)in_sizes; (void)n_in; (void)out_size; (void)ws_size;
  const int*   tok  = (const int*)d_in[0];
  const float* emb  = (const float*)d_in[1];
  const float* Wx   = (const float*)d_in[2];
  const float* Ul   = (const float*)d_in[3];
  const float* Ur   = (const float*)d_in[4];
  const float* bias = (const float*)d_in[5];
  float* out = (float*)d_out;

  char* ws = (char*)d_ws;
  size_t off = 0;
  __hip_bfloat16* Wb0t = (__hip_bfloat16*)(ws + off); off += (size_t)NGATE*320*2;   // 1.6 MB
  __hip_bfloat16* Wb1t = (__hip_bfloat16*)(ws + off); off += (size_t)NGATE*1024*2;  // 5.2 MB
  __hip_bfloat16* hA   = (__hip_bfloat16*)(ws + off); off += (size_t)32768*HH*2;    // 32 MB (even levels)
  __hip_bfloat16* hB   = (__hip_bfloat16*)(ws + off); off += (size_t)16384*HH*2;    // 16 MB (odd levels)
  float*          cA   = (float*)(ws + off);          off += (size_t)32768*HH*4;    // 64 MB (even levels)
  float*          cB   = (float*)(ws + off);          off += (size_t)16384*HH*4;    // 32 MB (odd levels)
  __hip_bfloat16* A0   = (__hip_bfloat16*)cB;   // alias: A0 dead before cB first written (level 1)

  // weight prep (bf16, transposed [N][K])
  transpose_cvt<<<dim3(5, 40), 256, 0, stream>>>(Wx, Wb0t, DD, 320, 0);
  transpose_cvt<<<dim3(8, 40), 256, 0, stream>>>(Ul, Wb1t, HH, 1024, 0);
  transpose_cvt<<<dim3(8, 40), 256, 0, stream>>>(Ur, Wb1t, HH, 1024, 512);
  // embedding gather -> bf16 A0 [32768][320]
  embed_cvt<<<dim3(5, 8192), dim3(64,4), 0, stream>>>(tok, emb, A0);

  // level 0: M=32768, K=320  (BM=256)
  gemm_cell<128><<<(32768/256)*8, 512, 0, stream>>>(A0, Wb0t, 320, bias, nullptr,
                                                    out, hA, cA, 8, 0);
  // levels 1..8: M = 32768>>k, K=1024
  for (int k = 1; k <= 8; ++k) {
    int M = 32768 >> k;
    int sc = HH - (HH >> k);
    const __hip_bfloat16* Ain = (k & 1) ? hA : hB;
    __hip_bfloat16*       hO  = (k & 1) ? hB : hA;
    const float*          cI  = (k & 1) ? cA : cB;
    float*                cO  = (k & 1) ? cB : cA;
    if (M >= 8192) {
      gemm_cell<128><<<(M/256)*8, 512, 0, stream>>>(Ain, Wb1t, 1024, bias, cI,
                                                    out, hO, cO, 8 - k, sc);
    } else {
      gemm_cell<64><<<(M/128)*8, 512, 0, stream>>>(Ain, Wb1t, 1024, bias, cI,
                                                   out, hO, cO, 8 - k, sc);
    }
  }
}